// Round 15
// baseline (132.139 us; speedup 1.0000x reference)
//
#include <hip/hip_runtime.h>
#include <stdint.h>

// Problem constants
#define S_LEN 2048
#define D_DIM 1024
#define NB 2
#define NH 16
#define NE 64
#define N_COLS (3 * NH * NE)  // 3072 (Q | K | V column blocks)
#define K_DIM D_DIM           // 1024

typedef unsigned short u16;
typedef unsigned int u32;
typedef u16 u16x8 __attribute__((ext_vector_type(8)));
typedef __bf16 bf16x8 __attribute__((ext_vector_type(8)));
typedef float f32x4 __attribute__((ext_vector_type(4)));

__device__ __forceinline__ u16 f2b(float f) {
  u32 u = __builtin_bit_cast(u32, f);
  return (u16)((u + 0x7FFFu + ((u >> 16) & 1u)) >> 16);  // RNE
}

__device__ __forceinline__ void gload_lds16(const void* g, void* l) {
  __builtin_amdgcn_global_load_lds(
      (const __attribute__((address_space(1))) u32*)g,
      (__attribute__((address_space(3))) u32*)l, 16, 0, 0);
}

// ---------- merged prep: blocks [0,2048) convert x; [2048,2816) transpose W ----------
__global__ __launch_bounds__(256) void k_prep(const float* __restrict__ x,
                                              const float* __restrict__ Wq,
                                              const float* __restrict__ Wk,
                                              const float* __restrict__ Wv,
                                              u16* __restrict__ xb,
                                              u16* __restrict__ Wt) {
  __shared__ u16 tile[64][65];
  int bid = blockIdx.x;
  int t = threadIdx.x;
  if (bid < 2048) {
    size_t i = (size_t)bid * 256 + t;
    const float4* xf = (const float4*)x;
    float4 a = xf[2 * i], c = xf[2 * i + 1];
    u16x8 o;
    o[0] = f2b(a.x); o[1] = f2b(a.y); o[2] = f2b(a.z); o[3] = f2b(a.w);
    o[4] = f2b(c.x); o[5] = f2b(c.y); o[6] = f2b(c.z); o[7] = f2b(c.w);
    *(u16x8*)(xb + 8 * i) = o;
  } else {
    int wbid = bid - 2048;             // proj*256 + h*16 + kb
    int kb = wbid & 15;
    int h = (wbid >> 4) & 15;
    int proj = wbid >> 8;
    const float* W = (proj == 0) ? Wq : ((proj == 1) ? Wk : Wv);
    int k0 = kb * 64;
    int e = t & 63, kr = t >> 6;
    const float* src = W + ((size_t)h * D_DIM + k0 + kr * 16) * NE + e;
#pragma unroll
    for (int j = 0; j < 16; ++j) tile[kr * 16 + j][e] = f2b(src[(size_t)j * NE]);
    __syncthreads();
    int e2 = t >> 2, kc = (t & 3) * 16;
    u16x8 o0, o1;
#pragma unroll
    for (int j = 0; j < 8; ++j) { o0[j] = tile[kc + j][e2]; o1[j] = tile[kc + 8 + j][e2]; }
    size_t n = (size_t)proj * 1024 + h * 64 + e2;
    u16* dst = Wt + n * K_DIM + k0 + kc;
    *(u16x8*)dst = o0;
    *(u16x8*)(dst + 8) = o1;
  }
}

// ------------- GEMM: qkv[4096,3072] = xb[4096,1024] @ Wt[3072,1024]^T -------------
__global__ __launch_bounds__(256) void k_gemm(const u16* __restrict__ A,
                                              const u16* __restrict__ Bt,
                                              u16* __restrict__ C) {
  __shared__ __align__(16) u16 As[128 * 64];
  __shared__ __align__(16) u16 Bs[128 * 64];
  int t = threadIdx.x;
  int lane = t & 63, w = t >> 6;
  int wr = (w >> 1) * 64, wc = (w & 1) * 64;
  int bid = blockIdx.x;
  int xcd = bid & 7, r0 = bid >> 3;          // r0 in [0,96)
  int m0 = (r0 / 3) * 128;
  int n0 = (xcd * 3 + (r0 % 3)) * 128;
  float qscale = ((n0 + wc) < 1024) ? 0.18033688f : 1.0f;  // 0.125*log2e
  f32x4 acc[4][4];
#pragma unroll
  for (int m = 0; m < 4; m++)
#pragma unroll
    for (int n = 0; n < 4; n++)
#pragma unroll
      for (int j = 0; j < 4; j++) acc[m][n][j] = 0.f;

  for (int k0 = 0; k0 < K_DIM; k0 += 64) {
#pragma unroll
    for (int i = 0; i < 4; ++i) {
      int ci = i * 256 + t;
      int row = ci >> 3, c = ci & 7;
      int cs = c ^ (row & 7);
      gload_lds16(A + (size_t)(m0 + row) * K_DIM + k0 + cs * 8,
                  (char*)As + (size_t)(i * 256 + w * 64) * 16);
      gload_lds16(Bt + (size_t)(n0 + row) * K_DIM + k0 + cs * 8,
                  (char*)Bs + (size_t)(i * 256 + w * 64) * 16);
    }
    __syncthreads();
#pragma unroll
    for (int ks = 0; ks < 2; ++ks) {
      int kc = ks * 4 + (lane >> 4);
      bf16x8 af[4], bfr[4];
#pragma unroll
      for (int m = 0; m < 4; m++) {
        int r = wr + m * 16 + (lane & 15);
        af[m] = *(const bf16x8*)&As[r * 64 + ((kc ^ (r & 7)) * 8)];
      }
#pragma unroll
      for (int n = 0; n < 4; n++) {
        int r = wc + n * 16 + (lane & 15);
        bfr[n] = *(const bf16x8*)&Bs[r * 64 + ((kc ^ (r & 7)) * 8)];
      }
#pragma unroll
      for (int m = 0; m < 4; m++)
#pragma unroll
        for (int n = 0; n < 4; n++)
          acc[m][n] = __builtin_amdgcn_mfma_f32_16x16x32_bf16(af[m], bfr[n], acc[m][n], 0, 0, 0);
    }
    __syncthreads();
  }
#pragma unroll
  for (int m = 0; m < 4; m++) {
#pragma unroll
    for (int r = 0; r < 4; r++) {
      int row = m0 + wr + m * 16 + (lane >> 4) * 4 + r;
#pragma unroll
      for (int n = 0; n < 4; n++) {
        int col = n0 + wc + n * 16 + (lane & 15);
        C[(size_t)row * N_COLS + col] = f2b(acc[m][n][r] * qscale);
      }
    }
  }
}

// ---- attention helpers (256-thread block) ----
__device__ __forceinline__ void stage_k(const u16* kb_, u16* kdst, int kv0, int t, int w) {
#pragma unroll
  for (int i = 0; i < 2; ++i) {
    int ci = i * 256 + t;
    int row = ci >> 3, c = ci & 7;
    int cs = c ^ (row & 7);
    gload_lds16(kb_ + (size_t)(kv0 + row) * N_COLS + cs * 8,
                (char*)kdst + (size_t)(i * 256 + w * 64) * 16);  // wave-uniform base
  }
}

// pi-ordered V write: thread covers kv pair (kvA, kvA+16), e-chunk vec*8..+7.
// pi(kv) = ((kv>>5)<<5)|((kv&15)<<1)|((kv>>4)&1); element (e,kv) at byte
// e*128 + ((pi>>3)^sw(e))*16 + (pi&7)*2, sw(e) = (e&7)^(e>>3). Pair (kvA,kvA+16)
// has adjacent pi -> one u32 write. Read side: slot (4ks+hi) is 8 contiguous u16
// = 1 b128, covering kv = 32ks+16(d&1)+4hi+(d>>1) for d=0..7.
__device__ __forceinline__ void vwrite(u16* vt, u16x8 va, u16x8 vb2, int kvA, int vec) {
  int pi_hi = ((kvA >> 5) << 2) | ((kvA & 15) >> 2);
  int pi_lo = (kvA & 3) * 4;     // byte offset within slot
#pragma unroll
  for (int j = 0; j < 8; ++j) {
    int e = vec * 8 + j;
    int sw = (e & 7) ^ (e >> 3);
    *(u32*)((char*)vt + e * 128 + ((pi_hi ^ sw) * 16) + pi_lo) =
        (u32)va[j] | ((u32)vb2[j] << 16);
  }
}

// --- flash attention, causal, two-strip register-P, shared V-fragments, b128 V ---
// Grid 512 = 8 xcd x 64: x=bid&7, g=bid>>3; bh=x*4+(g&3) (4 heads' K/V = 2 MB per
// XCD L2); qb=15-(g>>2) (LPT longest-first). Block covers q in [qb*128, qb*128+128)
// as strips A (wave rows qb*128+w*16+l15) and B (+64). Per kv-tile: K fragment regs
// feed both strips' QK^T (mfma(K,Q) swapped -> P register-local per strip); PV's V
// fragment depends only on (ks,ef) -> ONE b128 load serves both strips' MFMAs.
// LDS cycles per q-row ~halved vs r12. Strip A masks at ti==nt-2, skips ti==nt-1;
// strip B masks at ti==nt-1. No-max exp2 softmax (Q pre-scaled in GEMM).
__global__ __launch_bounds__(256) void k_attn(const u16* __restrict__ qkv,
                                              float* __restrict__ out) {
  __shared__ __align__(16) u16 Ks[2][64 * 64];
  __shared__ __align__(16) u16 Vt[2][64 * 64];
  int t = threadIdx.x;
  int lane = t & 63, w = t >> 6;
  int hi = lane >> 4, l15 = lane & 15;
  int bid = blockIdx.x;                 // 0..511
  int x = bid & 7, g = bid >> 3;
  int bh = x * 4 + (g & 3);
  int qb = 15 - (g >> 2);
  int b = bh >> 4, h = bh & 15;
  const u16* qb_ = qkv + (size_t)b * S_LEN * N_COLS + h * NE;
  const u16* kb_ = qb_ + 1024;
  const u16* vb_ = qb_ + 2048;
  int w2 = t >> 3, vec = t & 7;
  int kvA0 = (w2 & 15) | ((w2 & 16) << 1);   // 0..15, 32..47 (pair partner +16)

  int q0 = qb * 128;
  int nt = 2 * qb + 2;
  int wqA = q0 + w * 16;                // strip A wave q base; strip B = +64
  int myqA = wqA + l15, myqB = myqA + 64;

  bf16x8 qfA[2], qfB[2];
#pragma unroll
  for (int ks = 0; ks < 2; ks++) {
    qfA[ks] = *(const bf16x8*)(qb_ + (size_t)(wqA + l15) * N_COLS + ks * 32 + hi * 8);
    qfB[ks] = *(const bf16x8*)(qb_ + (size_t)(wqA + 64 + l15) * N_COLS + ks * 32 + hi * 8);
  }

  f32x4 oA[4], oB[4];
#pragma unroll
  for (int i = 0; i < 4; i++)
#pragma unroll
    for (int j = 0; j < 4; j++) { oA[i][j] = 0.f; oB[i][j] = 0.f; }
  float lsA = 0.f, lsB = 0.f;

  // prologue: stage tile 0 into buffer 0
  stage_k(kb_, Ks[0], 0, t, w);
  {
    const u16* vs = vb_ + (size_t)kvA0 * N_COLS + vec * 8;
    u16x8 va = *(const u16x8*)vs;
    u16x8 vb2 = *(const u16x8*)(vs + 16 * N_COLS);
    vwrite(Vt[0], va, vb2, kvA0, vec);
  }
  __syncthreads();

  int cur = 0;
  for (int ti = 0; ti < nt; ++ti) {
    int kv0 = ti * 64;
    bool pf = (ti + 1 < nt);
    u16x8 va, vb2;
    if (pf) {
      const u16* vs = vb_ + (size_t)(kv0 + 64 + kvA0) * N_COLS + vec * 8;
      va = *(const u16x8*)vs;            // in flight during QK^T+softmax
      vb2 = *(const u16x8*)(vs + 16 * N_COLS);
      stage_k(kb_, Ks[cur ^ 1], kv0 + 64, t, w);
    }
    bool doA = (ti != nt - 1);           // last tile fully masked for strip A
    bool maskA = (ti == nt - 2);
    bool maskB = (ti == nt - 1);

    // S^T = K Q both strips: each kf register feeds 2 MFMAs
    f32x4 sA[4], sB[4];
#pragma unroll
    for (int f = 0; f < 4; f++)
#pragma unroll
      for (int j = 0; j < 4; j++) { sA[f][j] = 0.f; sB[f][j] = 0.f; }
    __builtin_amdgcn_s_setprio(1);
#pragma unroll
    for (int ks = 0; ks < 2; ks++) {
      int kc = ks * 4 + hi;
#pragma unroll
      for (int f = 0; f < 4; f++) {
        int r = f * 16 + l15;
        bf16x8 kf = *(const bf16x8*)&Ks[cur][r * 64 + ((kc ^ (r & 7)) * 8)];
        sB[f] = __builtin_amdgcn_mfma_f32_16x16x32_bf16(kf, qfB[ks], sB[f], 0, 0, 0);
        if (doA)
          sA[f] = __builtin_amdgcn_mfma_f32_16x16x32_bf16(kf, qfA[ks], sA[f], 0, 0, 0);
      }
    }
    __builtin_amdgcn_s_setprio(0);

    // no-max softmax both strips: p = exp2(s); per-strip diagonal mask
    if (doA) {
#pragma unroll
      for (int f = 0; f < 4; f++)
#pragma unroll
        for (int r = 0; r < 4; r++) {
          float p = __builtin_amdgcn_exp2f(sA[f][r]);
          if (maskA) {
            int kv = kv0 + f * 16 + 4 * hi + r;
            p = (kv <= myqA) ? p : 0.f;
          }
          sA[f][r] = p;
          lsA += p;
        }
    }
#pragma unroll
    for (int f = 0; f < 4; f++)
#pragma unroll
      for (int r = 0; r < 4; r++) {
        float p = __builtin_amdgcn_exp2f(sB[f][r]);
        if (maskB) {
          int kv = kv0 + f * 16 + 4 * hi + r;
          p = (kv <= myqB) ? p : 0.f;
        }
        sB[f][r] = p;
        lsB += p;
      }

    // T14 write-late: V prefetch regs -> next buffer
    if (pf) vwrite(Vt[cur ^ 1], va, vb2, kvA0, vec);

    // PV: pa register-local per strip; ONE b128 V fragment serves both strips.
    // pa[d] = P[kv = 32ks + 16(d&1) + 4hi + (d>>1)] = s[2ks+(d&1)][d>>1]
    __builtin_amdgcn_s_setprio(1);
#pragma unroll
    for (int ks = 0; ks < 2; ks++) {
      bf16x8 paA, paB;
#pragma unroll
      for (int d = 0; d < 8; d++) {
        paA[d] = (__bf16)sA[2 * ks + (d & 1)][d >> 1];
        paB[d] = (__bf16)sB[2 * ks + (d & 1)][d >> 1];
      }
#pragma unroll
      for (int ef = 0; ef < 4; ef++) {
        int e = ef * 16 + l15;
        int sw = (e & 7) ^ (e >> 3);
        bf16x8 vbf = *(const bf16x8*)((const char*)Vt[cur] + e * 128 +
                                      (((4 * ks + hi) ^ sw) * 16));
        oB[ef] = __builtin_amdgcn_mfma_f32_16x16x32_bf16(paB, vbf, oB[ef], 0, 0, 0);
        if (doA)
          oA[ef] = __builtin_amdgcn_mfma_f32_16x16x32_bf16(paA, vbf, oA[ef], 0, 0, 0);
      }
    }
    __builtin_amdgcn_s_setprio(0);
    __syncthreads();
    cur ^= 1;
  }

  // epilogue: complete row-sums, redistribute, normalize, store both strips
  lsA += __shfl_xor(lsA, 16);
  lsA += __shfl_xor(lsA, 32);
  lsB += __shfl_xor(lsB, 16);
  lsB += __shfl_xor(lsB, 32);
#pragma unroll
  for (int r = 0; r < 4; r++) {
    float la = __shfl(lsA, 4 * hi + r);
    float lb = __shfl(lsB, 4 * hi + r);
    float invA = 1.0f / la, invB = 1.0f / lb;
    int qA = wqA + 4 * hi + r;
#pragma unroll
    for (int ef = 0; ef < 4; ef++) {
      int col = h * NE + ef * 16 + l15;
      size_t base = (size_t)b * S_LEN;
      out[(base + qA) * (NH * NE) + col] = oA[ef][r] * invA;
      out[(base + qA + 64) * (NH * NE) + col] = oB[ef][r] * invB;
    }
  }
}

extern "C" void kernel_launch(void* const* d_in, const int* in_sizes, int n_in,
                              void* d_out, int out_size, void* d_ws, size_t ws_size,
                              hipStream_t stream) {
  const float* x = (const float*)d_in[0];
  const float* Wq = (const float*)d_in[1];
  const float* Wk = (const float*)d_in[2];
  const float* Wv = (const float*)d_in[3];
  float* out = (float*)d_out;

  char* ws = (char*)d_ws;
  u16* xb = (u16*)ws;                          // 4096*1024*2  = 8 MB
  u16* Wt = (u16*)(ws + (8u << 20));           // 3072*1024*2  = 6 MB
  u16* qkv = (u16*)(ws + (14u << 20));         // 4096*3072*2  = 24 MB

  k_prep<<<dim3(2816), dim3(256), 0, stream>>>(x, Wq, Wk, Wv, xb, Wt);
  k_gemm<<<dim3(768), dim3(256), 0, stream>>>(xb, Wt, qkv);
  k_attn<<<dim3(512), dim3(256), 0, stream>>>(qkv, out);
}

// Round 16
// 86.294 us; speedup vs baseline: 1.5313x; 1.5313x over previous
//
#include <hip/hip_runtime.h>
#include <stdint.h>

// Problem constants
#define S_LEN 2048
#define D_DIM 1024
#define NB 2
#define NH 16
#define NE 64
#define N_COLS (3 * NH * NE)  // 3072 GEMM logical cols (Q | K | V)
#define QK_COLS 2048          // stored cols of qk buffer (Q | K)
#define K_DIM D_DIM           // 1024

typedef unsigned short u16;
typedef unsigned int u32;
typedef unsigned long long u64;
typedef u16 u16x8 __attribute__((ext_vector_type(8)));
typedef __bf16 bf16x8 __attribute__((ext_vector_type(8)));
typedef float f32x4 __attribute__((ext_vector_type(4)));

__device__ __forceinline__ u16 f2b(float f) {
  u32 u = __builtin_bit_cast(u32, f);
  return (u16)((u + 0x7FFFu + ((u >> 16) & 1u)) >> 16);  // RNE
}

__device__ __forceinline__ void gload_lds16(const void* g, void* l) {
  __builtin_amdgcn_global_load_lds(
      (const __attribute__((address_space(1))) u32*)g,
      (__attribute__((address_space(3))) u32*)l, 16, 0, 0);
}

// ---------- merged prep: blocks [0,2048) convert x; [2048,2816) transpose W ----------
__global__ __launch_bounds__(256) void k_prep(const float* __restrict__ x,
                                              const float* __restrict__ Wq,
                                              const float* __restrict__ Wk,
                                              const float* __restrict__ Wv,
                                              u16* __restrict__ xb,
                                              u16* __restrict__ Wt) {
  __shared__ u16 tile[64][65];
  int bid = blockIdx.x;
  int t = threadIdx.x;
  if (bid < 2048) {
    size_t i = (size_t)bid * 256 + t;
    const float4* xf = (const float4*)x;
    float4 a = xf[2 * i], c = xf[2 * i + 1];
    u16x8 o;
    o[0] = f2b(a.x); o[1] = f2b(a.y); o[2] = f2b(a.z); o[3] = f2b(a.w);
    o[4] = f2b(c.x); o[5] = f2b(c.y); o[6] = f2b(c.z); o[7] = f2b(c.w);
    *(u16x8*)(xb + 8 * i) = o;
  } else {
    int wbid = bid - 2048;             // proj*256 + h*16 + kb
    int kb = wbid & 15;
    int h = (wbid >> 4) & 15;
    int proj = wbid >> 8;
    const float* W = (proj == 0) ? Wq : ((proj == 1) ? Wk : Wv);
    int k0 = kb * 64;
    int e = t & 63, kr = t >> 6;
    const float* src = W + ((size_t)h * D_DIM + k0 + kr * 16) * NE + e;
#pragma unroll
    for (int j = 0; j < 16; ++j) tile[kr * 16 + j][e] = f2b(src[(size_t)j * NE]);
    __syncthreads();
    int e2 = t >> 2, kc = (t & 3) * 16;
    u16x8 o0, o1;
#pragma unroll
    for (int j = 0; j < 8; ++j) { o0[j] = tile[kc + j][e2]; o1[j] = tile[kc + 8 + j][e2]; }
    size_t n = (size_t)proj * 1024 + h * 64 + e2;
    u16* dst = Wt + n * K_DIM + k0 + kc;
    *(u16x8*)dst = o0;
    *(u16x8*)(dst + 8) = o1;
  }
}

// ------------- GEMM: [4096,3072] = xb[4096,1024] @ Wt[3072,1024]^T -------------
// Q|K cols (<2048) -> qk[row][2048] (Q pre-scaled by 0.125*log2e for exp2 softmax).
// V cols (>=2048) -> VT[(b*16+h)*64+e][posg(s)] u16: transposed + kv-permuted so
// attention's PV A-fragment k-map (kv=32ks+16(j>>2)+4hi+(j&3)) is 8 contiguous u16
// -> V stages via gload_lds DMA and reads 1 b128/fragment.
// posg(s) = (s&~63)|(s&32)|((s&12)<<1)|((s&16)>>2)|(s&3). acc r-index walks s
// consecutively (s_base%4==0) -> one aligned u64 store per (m,n).
__global__ __launch_bounds__(256) void k_gemm(const u16* __restrict__ A,
                                              const u16* __restrict__ Bt,
                                              u16* __restrict__ Cqk,
                                              u16* __restrict__ VT) {
  __shared__ __align__(16) u16 As[128 * 64];
  __shared__ __align__(16) u16 Bs[128 * 64];
  int t = threadIdx.x;
  int lane = t & 63, w = t >> 6;
  int hi = lane >> 4, l15 = lane & 15;
  int wr = (w >> 1) * 64, wc = (w & 1) * 64;
  int bid = blockIdx.x;
  int xcd = bid & 7, r0 = bid >> 3;          // r0 in [0,96)
  int m0 = (r0 / 3) * 128;
  int n0 = (xcd * 3 + (r0 % 3)) * 128;
  bool isV = (n0 >= 2048);                   // block-uniform
  float qscale = ((n0 + wc) < 1024) ? 0.18033688f : 1.0f;  // 0.125*log2e
  f32x4 acc[4][4];
#pragma unroll
  for (int m = 0; m < 4; m++)
#pragma unroll
    for (int n = 0; n < 4; n++)
#pragma unroll
      for (int j = 0; j < 4; j++) acc[m][n][j] = 0.f;

  for (int k0 = 0; k0 < K_DIM; k0 += 64) {
#pragma unroll
    for (int i = 0; i < 4; ++i) {
      int ci = i * 256 + t;
      int row = ci >> 3, c = ci & 7;
      int cs = c ^ (row & 7);
      gload_lds16(A + (size_t)(m0 + row) * K_DIM + k0 + cs * 8,
                  (char*)As + (size_t)(i * 256 + w * 64) * 16);
      gload_lds16(Bt + (size_t)(n0 + row) * K_DIM + k0 + cs * 8,
                  (char*)Bs + (size_t)(i * 256 + w * 64) * 16);
    }
    __syncthreads();
#pragma unroll
    for (int ks = 0; ks < 2; ++ks) {
      int kc = ks * 4 + hi;
      bf16x8 af[4], bfr[4];
#pragma unroll
      for (int m = 0; m < 4; m++) {
        int r = wr + m * 16 + l15;
        af[m] = *(const bf16x8*)&As[r * 64 + ((kc ^ (r & 7)) * 8)];
      }
#pragma unroll
      for (int n = 0; n < 4; n++) {
        int r = wc + n * 16 + l15;
        bfr[n] = *(const bf16x8*)&Bs[r * 64 + ((kc ^ (r & 7)) * 8)];
      }
#pragma unroll
      for (int m = 0; m < 4; m++)
#pragma unroll
        for (int n = 0; n < 4; n++)
          acc[m][n] = __builtin_amdgcn_mfma_f32_16x16x32_bf16(af[m], bfr[n], acc[m][n], 0, 0, 0);
    }
    __syncthreads();
  }

  if (!isV) {
#pragma unroll
    for (int m = 0; m < 4; m++) {
#pragma unroll
      for (int r = 0; r < 4; r++) {
        int row = m0 + wr + m * 16 + hi * 4 + r;
#pragma unroll
        for (int n = 0; n < 4; n++) {
          int col = n0 + wc + n * 16 + l15;
          Cqk[(size_t)row * QK_COLS + col] = f2b(acc[m][n][r] * qscale);
        }
      }
    }
  } else {
#pragma unroll
    for (int m = 0; m < 4; m++) {
      int row_s = m0 + wr + m * 16 + hi * 4;      // s_base, %4 == 0
      int bb = row_s >> 11, s = row_s & 2047;
      int pos = (s & ~63) | (s & 32) | ((s & 12) << 1) | ((s & 16) >> 2) | (s & 3);
#pragma unroll
      for (int n = 0; n < 4; n++) {
        int col = n0 + wc + n * 16 + l15 - 2048;  // 0..1023
        int hh = col >> 6, e = col & 63;
        u64 pk = (u64)f2b(acc[m][n][0]) | ((u64)f2b(acc[m][n][1]) << 16) |
                 ((u64)f2b(acc[m][n][2]) << 32) | ((u64)f2b(acc[m][n][3]) << 48);
        *(u64*)(VT + ((size_t)((bb * 16 + hh) * 64 + e)) * S_LEN + pos) = pk;
      }
    }
  }
}

// ---- attention helpers (256-thread block) ----
__device__ __forceinline__ void stage_k(const u16* kb_, u16* kdst, int kv0, int t, int w) {
#pragma unroll
  for (int i = 0; i < 2; ++i) {
    int ci = i * 256 + t;
    int row = ci >> 3, c = ci & 7;
    int cs = c ^ (row & 7);
    gload_lds16(kb_ + (size_t)(kv0 + row) * QK_COLS + cs * 8,
                (char*)kdst + (size_t)(i * 256 + w * 64) * 16);  // wave-uniform base
  }
}

// V^T stage: VT rows are e (stride S_LEN u16), tile cols [kv0, kv0+64) contiguous
// (kv-permuted at GEMM store). Same XOR-swizzled-source DMA pattern as K.
__device__ __forceinline__ void stage_v(const u16* vtb_, u16* vdst, int kv0, int t, int w) {
#pragma unroll
  for (int i = 0; i < 2; ++i) {
    int ci = i * 256 + t;
    int row = ci >> 3, c = ci & 7;
    int cs = c ^ (row & 7);
    gload_lds16(vtb_ + (size_t)row * S_LEN + kv0 + cs * 8,
                (char*)vdst + (size_t)(i * 256 + w * 64) * 16);
  }
}

// ------- flash attention, causal, swapped-QK^T register-P, DMA-staged V^T -------
// r12 structure exactly: 1024 blocks x 4 waves; x=bid&7, g=bid>>3, bh=x*4+(g&3)
// (4 heads' K/V per XCD L2), qt=31-(g>>2) (LPT). Wave owns 16 q rows. QK^T as
// mfma(K,Q) -> P register-local. V^T pre-transposed+permuted by GEMM -> staged
// via gload_lds DMA (no reg-staging, no ds_writes) and PV reads 1 b128/fragment;
// A/B k-maps agree (kv = 32ks+16(j>>2)+4hi+(j&3)) so dot products are exact.
// No-max exp2 softmax (Q pre-scaled in GEMM); per-lane scalar lsum.
__global__ __launch_bounds__(256) void k_attn(const u16* __restrict__ qk,
                                              const u16* __restrict__ VT,
                                              float* __restrict__ out) {
  __shared__ __align__(16) u16 Ks[2][64 * 64];
  __shared__ __align__(16) u16 Vs[2][64 * 64];
  int t = threadIdx.x;
  int lane = t & 63, w = t >> 6;
  int hi = lane >> 4, l15 = lane & 15;
  int bid = blockIdx.x;                 // 0..1023
  int x = bid & 7, g = bid >> 3;
  int bh = x * 4 + (g & 3);
  int qt = 31 - (g >> 2);
  int b = bh >> 4, h = bh & 15;
  const u16* qb_ = qk + (size_t)b * S_LEN * QK_COLS + h * NE;
  const u16* kb_ = qb_ + 1024;
  const u16* vtb_ = VT + (size_t)bh * 64 * S_LEN;

  int q0 = qt * 64;
  int nt = qt + 1;
  int wqb = q0 + w * 16;                // wave q base; lane q = wqb + l15

  bf16x8 qf[2];
#pragma unroll
  for (int ks = 0; ks < 2; ks++)
    qf[ks] = *(const bf16x8*)(qb_ + (size_t)(wqb + l15) * QK_COLS + ks * 32 + hi * 8);

  f32x4 o[4];
#pragma unroll
  for (int i = 0; i < 4; i++)
#pragma unroll
    for (int j = 0; j < 4; j++) o[i][j] = 0.f;
  float lsum = 0.f;
  int myq = wqb + l15;

  // prologue: stage tile 0 into buffer 0
  stage_k(kb_, Ks[0], 0, t, w);
  stage_v(vtb_, Vs[0], 0, t, w);
  __syncthreads();

  int cur = 0;
  for (int ti = 0; ti < nt; ++ti) {
    int kv0 = ti * 64;
    bool pf = (ti + 1 < nt);
    if (pf) {
      stage_k(kb_, Ks[cur ^ 1], kv0 + 64, t, w);
      stage_v(vtb_, Vs[cur ^ 1], kv0 + 64, t, w);
    }

    // S^T = K Q : s[f][r] = S[kv = kv0+16f+4hi+r][q = myq]
    f32x4 s[4];
#pragma unroll
    for (int f = 0; f < 4; f++)
#pragma unroll
      for (int j = 0; j < 4; j++) s[f][j] = 0.f;
    __builtin_amdgcn_s_setprio(1);
#pragma unroll
    for (int ks = 0; ks < 2; ks++) {
      int kc = ks * 4 + hi;
#pragma unroll
      for (int f = 0; f < 4; f++) {
        int r = f * 16 + l15;
        bf16x8 kf = *(const bf16x8*)&Ks[cur][r * 64 + ((kc ^ (r & 7)) * 8)];
        s[f] = __builtin_amdgcn_mfma_f32_16x16x32_bf16(kf, qf[ks], s[f], 0, 0, 0);
      }
    }
    __builtin_amdgcn_s_setprio(0);

    // no-max softmax: p = exp2(s); mask last tile per-element; lsum per-lane (q fixed)
    bool diag = (ti == nt - 1);
#pragma unroll
    for (int f = 0; f < 4; f++) {
#pragma unroll
      for (int r = 0; r < 4; r++) {
        float p = __builtin_amdgcn_exp2f(s[f][r]);
        if (diag) {
          int kv = kv0 + f * 16 + 4 * hi + r;
          p = (kv <= myq) ? p : 0.f;
        }
        s[f][r] = p;
        lsum += p;
      }
    }

    // PV: pa register-local (pa[j] = s[2ks+(j>>2)][j&3], kv=32ks+16(j>>2)+4hi+(j&3));
    // V fragment = ONE b128 from Vs (kv-permuted layout), chunk (4ks+hi)^(e&7).
    __builtin_amdgcn_s_setprio(1);
#pragma unroll
    for (int ks = 0; ks < 2; ks++) {
      bf16x8 pa;
#pragma unroll
      for (int j = 0; j < 4; j++) {
        pa[j] = (__bf16)s[2 * ks][j];
        pa[4 + j] = (__bf16)s[2 * ks + 1][j];
      }
#pragma unroll
      for (int ef = 0; ef < 4; ef++) {
        int e = ef * 16 + l15;
        bf16x8 vbf = *(const bf16x8*)&Vs[cur][e * 64 + (((4 * ks + hi) ^ (e & 7)) * 8)];
        o[ef] = __builtin_amdgcn_mfma_f32_16x16x32_bf16(pa, vbf, o[ef], 0, 0, 0);
      }
    }
    __builtin_amdgcn_s_setprio(0);
    __syncthreads();
    cur ^= 1;
  }

  // epilogue: complete row-sum across hi groups, redistribute, normalize, store.
  lsum += __shfl_xor(lsum, 16);
  lsum += __shfl_xor(lsum, 32);
#pragma unroll
  for (int r = 0; r < 4; r++) {
    float l = __shfl(lsum, 4 * hi + r);  // lane 4hi+r holds sum for q = wqb+4hi+r
    float inv = 1.0f / l;
    int q = wqb + 4 * hi + r;
#pragma unroll
    for (int ef = 0; ef < 4; ef++) {
      int col = h * NE + ef * 16 + l15;
      out[((size_t)b * S_LEN + q) * (NH * NE) + col] = o[ef][r] * inv;
    }
  }
}

extern "C" void kernel_launch(void* const* d_in, const int* in_sizes, int n_in,
                              void* d_out, int out_size, void* d_ws, size_t ws_size,
                              hipStream_t stream) {
  const float* x = (const float*)d_in[0];
  const float* Wq = (const float*)d_in[1];
  const float* Wk = (const float*)d_in[2];
  const float* Wv = (const float*)d_in[3];
  float* out = (float*)d_out;

  char* ws = (char*)d_ws;
  u16* xb = (u16*)ws;                          // 4096*1024*2  = 8 MB
  u16* Wt = (u16*)(ws + (8u << 20));           // 3072*1024*2  = 6 MB
  u16* qk = (u16*)(ws + (14u << 20));          // 4096*2048*2  = 16 MB
  u16* VT = (u16*)(ws + (30u << 20));          // 32*64*2048*2 = 8 MB

  k_prep<<<dim3(2816), dim3(256), 0, stream>>>(x, Wq, Wk, Wv, xb, Wt);
  k_gemm<<<dim3(768), dim3(256), 0, stream>>>(xb, Wt, qk, VT);
  k_attn<<<dim3(1024), dim3(256), 0, stream>>>(qk, VT, out);
}